// Round 1
// 442.908 us; speedup vs baseline: 1.6352x; 1.6352x over previous
//
#include <hip/hip_runtime.h>
#include <hip/hip_bf16.h>

// Attention aggregator: B=8, N=2048, D=512
//   S = X X^T (bf16 MFMA, fp32 acc), mask (adj==0 && q!=k) -> -9999999,
//   online row softmax, O = P X.  Output fp32.
// Round 9: latency-bound fix (all pipes were <12% busy, 87% stall at 1 wave/SIMD):
//   - pre-pass converts X fp32->bf16 into d_ws in LDS-ready 4x16-subtiled tile
//     layout: ws[b][kt][key>>2][d>>4][key&3][d&15]
//   - main kernel stages K-tiles via global_load_lds (width 16, async, no VGPR
//     round-trip), double-buffered, ONE barrier/iter (was 3)
//   - PV B-operand via ds_read_b64_tr_b16 from the same row-major subtiled
//     buffer: KsmT (2nd global read + 64 u16 scatter writes/thread/iter) deleted
//   - adj rows prefetched right after the barrier, BEFORE the gll issue, so the
//     compiler's wait for them is a counted vmcnt(8), not a drain
//   - Pbuf is wave-private: barrier C replaced by same-wave DS ordering
//     (asm ds_read_b128 + lgkmcnt(0) + sched_barrier(0))
// Compute semantics (fragment layouts, accumulation order, rounding) identical
// to the round-8 verified kernel -> absmax must stay 0.

typedef __attribute__((ext_vector_type(8))) short short8;    // 8 x bf16
typedef __attribute__((ext_vector_type(4))) short short4v;   // 4 x bf16 (tr-read dst)
typedef __attribute__((ext_vector_type(4))) float float4v;   // 4 x f32

#define NN 2048
#define DD 512
#define NB 8
#define QT 64
#define KT 32
#define NEGINF -9999999.0f
#define PB_S 40

// subtiled tile: 256 subtiles (4 keys x 16 d = 128 B each), 8 subtiles = 1 KB chunk,
// chunk padded +16 B in LDS to spread banks. 32 chunks per 32-key tile.
#define CH_STRIDE 1040
#define TILE_LDS  (32 * CH_STRIDE)          // 33280 B per tile buffer
#define TILE_WS   (KT * DD * 2)             // 32768 B per tile in workspace (dense)
#define K4_STRIDE (4 * CH_STRIDE)           // key-subtile-group stride = 4 chunks
#define WS_NEED   ((size_t)NB * (NN / KT) * TILE_WS)   // 16,777,216 B
#define TROFF(dt) ((((dt) >> 3) * CH_STRIDE) + (((dt) & 7) * 128))

#define GL2LDS(gsrc, ldst)                                              \
  __builtin_amdgcn_global_load_lds(                                     \
      (__attribute__((address_space(1))) void*)(gsrc),                  \
      (__attribute__((address_space(3))) void*)(ldst), 16, 0, 0)

__device__ __forceinline__ short f2bf(float x) {
  union { __hip_bfloat16 h; short s; } u; u.h = __float2bfloat16(x); return u.s;
}
__device__ __forceinline__ float expg(float d) {   // no inf/NaN path
  return (d < -80.f) ? 0.f : __expf(d);
}
__device__ __forceinline__ short8 cvt8(const float* p) {
  float4v u0 = *(const float4v*)(p);
  float4v u1 = *(const float4v*)(p + 4);
  short8 v;
  v[0] = f2bf(u0[0]); v[1] = f2bf(u0[1]); v[2] = f2bf(u0[2]); v[3] = f2bf(u0[3]);
  v[4] = f2bf(u1[0]); v[5] = f2bf(u1[1]); v[6] = f2bf(u1[2]); v[7] = f2bf(u1[3]);
  return v;
}
__device__ __forceinline__ unsigned lds_addr(const void* p) {
  return (unsigned)(size_t)(__attribute__((address_space(3))) const void*)p;
}

// ---------------- pre-pass: X fp32 -> bf16, subtiled tile layout ----------------
// ws short index within tile: (K4*32 + D16)*64 + r*16 + c  == u_local*8 layout below.
__global__ __launch_bounds__(256) void xcvt(const float* __restrict__ X,
                                            short* __restrict__ W) {
  const int u = blockIdx.x * 256 + threadIdx.x;     // 0 .. 2^20-1, exact
  const int c8  = (u & 1) * 8;
  const int r   = (u >> 1) & 3;
  const int D16 = (u >> 3) & 31;
  const int K4  = (u >> 8) & 7;
  const int ktb = u >> 11;                          // b*64 + kt, 0..511
  const int row = (ktb << 5) + (K4 << 2) + r;       // global row incl. batch
  const int col = (D16 << 4) + c8;
  short8 v = cvt8(X + (size_t)row * DD + col);
  *(short8*)(W + (size_t)u * 8) = v;
}

// ---------------- main kernel ----------------
__device__ __forceinline__ void stage_tile(const char* g, char* l, int wave, int lane) {
  const char* gp = g + lane * 16;
#pragma unroll
  for (int i = 0; i < 8; ++i) {
    const int ch = wave * 8 + i;                    // wave-uniform LDS dest
    GL2LDS(gp + ch * 1024, l + ch * CH_STRIDE);
  }
}

__global__ __launch_bounds__(256) void attn_fwd_v2(
    const float* __restrict__ X,    // [B][N][D] fp32 (for Q fragments)
    const short* __restrict__ W,    // bf16 subtiled tiles (from xcvt)
    const int*   __restrict__ adj,  // [B][N][N] int32
    float*       __restrict__ out)  // [B][N][D] fp32
{
  __shared__ __align__(16) char smem[2 * TILE_LDS + 4 * 16 * PB_S * 2];
  short* Pbuf = (short*)(smem + 2 * TILE_LDS);

  const int tid  = threadIdx.x;
  const int wave = tid >> 6;
  const int lane = tid & 63;
  const int l15  = lane & 15;
  const int quad = lane >> 4;

  const int b  = blockIdx.x >> 5;
  const int q0 = (blockIdx.x & 31) * QT;
  const int qw = q0 + wave * 16;

  const float* Xb  = X + (size_t)b * NN * DD;
  const char*  wsb = (const char*)W + (size_t)b * (NN / KT) * TILE_WS;

  // Q A-fragments: A[m=l15][k=quad*8+j], 16 chunks of K=32 covering D=512.
  short8 aq[16];
  {
    const float* xrow = Xb + (size_t)(qw + l15) * DD + quad * 8;
#pragma unroll
    for (int c = 0; c < 16; ++c) aq[c] = cvt8(xrow + c * 32);
  }

  float4v o[32];
#pragma unroll
  for (int i = 0; i < 32; ++i) o[i] = (float4v){0.f, 0.f, 0.f, 0.f};
  float m_i[4] = {-1e30f, -1e30f, -1e30f, -1e30f};
  float l_i[4] = {0.f, 0.f, 0.f, 0.f};

  const int* adjq = adj + ((size_t)b * NN + qw) * NN;

  // thread-invariant LDS address pieces
  const unsigned smem0   = lds_addr(smem);
  const unsigned qk_base = (unsigned)((l15 >> 2) * K4_STRIDE + (quad >> 1) * 128 +
                                      (l15 & 3) * 32 + (quad & 1) * 16);
  const unsigned pv_base = (unsigned)((2 * quad) * K4_STRIDE + l15 * 8);
  const unsigned pb_addr = lds_addr(Pbuf) +
                           (unsigned)(((wave * 16 + l15) * PB_S + quad * 8) * 2);

  stage_tile(wsb, smem, wave, lane);                // tile 0 -> buf 0

  for (int kt = 0; kt < NN / KT; ++kt) {
    const int kb = kt * KT;
    __syncthreads();   // drains vmcnt: tile-kt gll complete; prev-iter reads done

    // adj prefetch FIRST (so its wait is vmcnt(8), counting past the gll below)
    int am0[4], am1[4];
#pragma unroll
    for (int r = 0; r < 4; ++r) {
      const int* arow = adjq + (size_t)(quad * 4 + r) * NN + kb;
      am0[r] = arow[l15];
      am1[r] = arow[16 + l15];
    }
    if (kt + 1 < NN / KT)
      stage_tile(wsb + (size_t)(kt + 1) * TILE_WS,
                 smem + ((kt + 1) & 1) * TILE_LDS, wave, lane);

    const char*    lb  = smem + (kt & 1) * TILE_LDS;
    const unsigned lbo = smem0 + (unsigned)((kt & 1) * TILE_LDS);

    // ---- S = Xq * Xk^T ----
    float4v s0 = {0.f, 0.f, 0.f, 0.f}, s1 = {0.f, 0.f, 0.f, 0.f};
#pragma unroll
    for (int c = 0; c < 16; ++c) {
      const int off = (c >> 2) * CH_STRIDE + ((2 * c) & 7) * 128;
      short8 b0 = *(const short8*)(lb + qk_base + off);
      short8 b1 = *(const short8*)(lb + qk_base + off + 4 * K4_STRIDE);
      s0 = __builtin_amdgcn_mfma_f32_16x16x32_bf16(aq[c], b0, s0, 0, 0, 0);
      s1 = __builtin_amdgcn_mfma_f32_16x16x32_bf16(aq[c], b1, s1, 0, 0, 0);
    }

    // ---- mask + online softmax (C-layout: col=l15, row=quad*4+r) ----
#pragma unroll
    for (int r = 0; r < 4; ++r) {
      const int qr = quad * 4 + r;
      const int q  = qw + qr;
      float v0 = s0[r], v1 = s1[r];
      const int k0 = kb + l15, k1 = kb + 16 + l15;
      if (am0[r] == 0 && q != k0) v0 = NEGINF;   // adj+eye semantics
      if (am1[r] == 0 && q != k1) v1 = NEGINF;
      float mr = fmaxf(v0, v1);
      mr = fmaxf(mr, __shfl_xor(mr, 1));
      mr = fmaxf(mr, __shfl_xor(mr, 2));
      mr = fmaxf(mr, __shfl_xor(mr, 4));
      mr = fmaxf(mr, __shfl_xor(mr, 8));
      const float mnew  = fmaxf(m_i[r], mr);
      const float alpha = expg(m_i[r] - mnew);
      m_i[r] = mnew;
      const float p0 = expg(v0 - mnew);
      const float p1 = expg(v1 - mnew);
      float rs = p0 + p1;
      rs += __shfl_xor(rs, 1);
      rs += __shfl_xor(rs, 2);
      rs += __shfl_xor(rs, 4);
      rs += __shfl_xor(rs, 8);
      l_i[r] = l_i[r] * alpha + rs;
#pragma unroll
      for (int dt = 0; dt < 32; ++dt) o[dt][r] *= alpha;
      Pbuf[(wave * 16 + qr) * PB_S + l15]      = f2bf(p0);
      Pbuf[(wave * 16 + qr) * PB_S + 16 + l15] = f2bf(p1);
    }
    // no barrier: Pbuf is wave-private; same-wave DS ops execute in order.

    // ---- O += P * V (tr-reads from row-major subtiled tile) ----
    short8 ap;
    asm volatile("ds_read_b128 %0, %1" : "=v"(ap) : "v"(pb_addr) : "memory");
    const unsigned v0a = lbo + pv_base;          // subtile group K4=2*quad
#pragma unroll
    for (int g = 0; g < 8; ++g) {
      short4v t0, t1, t2, t3, u0, u1, u2, u3;
      asm volatile("ds_read_b64_tr_b16 %0, %1 offset:%2"
                   : "=v"(t0) : "v"(v0a), "i"(TROFF(4 * g + 0)));
      asm volatile("ds_read_b64_tr_b16 %0, %1 offset:%2"
                   : "=v"(t1) : "v"(v0a), "i"(TROFF(4 * g + 1)));
      asm volatile("ds_read_b64_tr_b16 %0, %1 offset:%2"
                   : "=v"(t2) : "v"(v0a), "i"(TROFF(4 * g + 2)));
      asm volatile("ds_read_b64_tr_b16 %0, %1 offset:%2"
                   : "=v"(t3) : "v"(v0a), "i"(TROFF(4 * g + 3)));
      asm volatile("ds_read_b64_tr_b16 %0, %1 offset:%2"
                   : "=v"(u0) : "v"(v0a), "i"(TROFF(4 * g + 0) + K4_STRIDE));
      asm volatile("ds_read_b64_tr_b16 %0, %1 offset:%2"
                   : "=v"(u1) : "v"(v0a), "i"(TROFF(4 * g + 1) + K4_STRIDE));
      asm volatile("ds_read_b64_tr_b16 %0, %1 offset:%2"
                   : "=v"(u2) : "v"(v0a), "i"(TROFF(4 * g + 2) + K4_STRIDE));
      asm volatile("ds_read_b64_tr_b16 %0, %1 offset:%2"
                   : "=v"(u3) : "v"(v0a), "i"(TROFF(4 * g + 3) + K4_STRIDE));
      asm volatile("s_waitcnt lgkmcnt(0)" ::: "memory");
      __builtin_amdgcn_sched_barrier(0);         // rule #18: pin MFMAs below the wait
      short8 bv0 = __builtin_shufflevector(t0, u0, 0, 1, 2, 3, 4, 5, 6, 7);
      short8 bv1 = __builtin_shufflevector(t1, u1, 0, 1, 2, 3, 4, 5, 6, 7);
      short8 bv2 = __builtin_shufflevector(t2, u2, 0, 1, 2, 3, 4, 5, 6, 7);
      short8 bv3 = __builtin_shufflevector(t3, u3, 0, 1, 2, 3, 4, 5, 6, 7);
      o[4 * g + 0] = __builtin_amdgcn_mfma_f32_16x16x32_bf16(ap, bv0, o[4 * g + 0], 0, 0, 0);
      o[4 * g + 1] = __builtin_amdgcn_mfma_f32_16x16x32_bf16(ap, bv1, o[4 * g + 1], 0, 0, 0);
      o[4 * g + 2] = __builtin_amdgcn_mfma_f32_16x16x32_bf16(ap, bv2, o[4 * g + 2], 0, 0, 0);
      o[4 * g + 3] = __builtin_amdgcn_mfma_f32_16x16x32_bf16(ap, bv3, o[4 * g + 3], 0, 0, 0);
    }
  }

  // ---- epilogue: normalize, store FP32 ----
#pragma unroll
  for (int r = 0; r < 4; ++r) {
    const float inv = 1.0f / fmaxf(l_i[r], 1e-30f);
    float* po = out + ((size_t)b * NN + (qw + quad * 4 + r)) * DD + l15;
#pragma unroll
    for (int dt = 0; dt < 32; ++dt)
      po[dt * 16] = o[dt][r] * inv;
  }
}

// ---------------- legacy (round-8 verified) fallback if ws too small ----------------
#define KSM_S 520
#define KST_S 40

__global__ __launch_bounds__(256, 2) void attn_fwd(
    const float* __restrict__ X,
    const int*   __restrict__ adj,
    float*       __restrict__ out)
{
  __shared__ short Ksm [KT * KSM_S];
  __shared__ short KsmT[DD * KST_S];
  __shared__ short Pb2[4 * 16 * PB_S];

  const int tid  = threadIdx.x;
  const int wave = tid >> 6;
  const int lane = tid & 63;
  const int l15  = lane & 15;
  const int quad = lane >> 4;

  const int b  = blockIdx.x >> 5;
  const int q0 = (blockIdx.x & 31) * QT;
  const int qw = q0 + wave * 16;

  const float* Xb = X + (size_t)b * NN * DD;

  short8 aq[16];
  {
    const float* xrow = Xb + (size_t)(qw + l15) * DD + quad * 8;
#pragma unroll
    for (int c = 0; c < 16; ++c) aq[c] = cvt8(xrow + c * 32);
  }

  float4v o[32];
#pragma unroll
  for (int i = 0; i < 32; ++i) o[i] = (float4v){0.f, 0.f, 0.f, 0.f};
  float m_i[4] = {-1e30f, -1e30f, -1e30f, -1e30f};
  float l_i[4] = {0.f, 0.f, 0.f, 0.f};

  const int* adjq = adj + ((size_t)b * NN + qw) * NN;

  for (int kt = 0; kt < NN / KT; ++kt) {
    const int kb = kt * KT;
    __syncthreads();
    {
      const int c = lane * 8;
#pragma unroll
      for (int it = 0; it < 8; ++it) {
        const int r = it * 4 + wave;
        *(short8*)(&Ksm[r * KSM_S + c]) = cvt8(Xb + (size_t)(kb + r) * DD + c);
      }
      const int rr = tid & 31;
      const int cg = (tid >> 5) * 8;
#pragma unroll
      for (int it = 0; it < 8; ++it) {
        const int col = it * 64 + cg;
        short8 v = cvt8(Xb + (size_t)(kb + rr) * DD + col);
#pragma unroll
        for (int j = 0; j < 8; ++j)
          KsmT[(col + j) * KST_S + rr] = v[j];
      }
    }
    __syncthreads();

    float4v s0 = {0.f, 0.f, 0.f, 0.f}, s1 = {0.f, 0.f, 0.f, 0.f};
#pragma unroll
    for (int c = 0; c < 16; ++c) {
      short8 b0 = *(const short8*)(&Ksm[l15 * KSM_S + c * 32 + quad * 8]);
      short8 b1 = *(const short8*)(&Ksm[(16 + l15) * KSM_S + c * 32 + quad * 8]);
      s0 = __builtin_amdgcn_mfma_f32_16x16x32_bf16(aq[c], b0, s0, 0, 0, 0);
      s1 = __builtin_amdgcn_mfma_f32_16x16x32_bf16(aq[c], b1, s1, 0, 0, 0);
    }

#pragma unroll
    for (int r = 0; r < 4; ++r) {
      const int qr = quad * 4 + r;
      const int q  = qw + qr;
      const int* arow = adjq + (size_t)qr * NN + kb;
      float v0 = s0[r], v1 = s1[r];
      const int k0 = kb + l15, k1 = kb + 16 + l15;
      if (arow[l15]      == 0 && q != k0) v0 = NEGINF;
      if (arow[16 + l15] == 0 && q != k1) v1 = NEGINF;
      float mr = fmaxf(v0, v1);
      mr = fmaxf(mr, __shfl_xor(mr, 1));
      mr = fmaxf(mr, __shfl_xor(mr, 2));
      mr = fmaxf(mr, __shfl_xor(mr, 4));
      mr = fmaxf(mr, __shfl_xor(mr, 8));
      const float mnew  = fmaxf(m_i[r], mr);
      const float alpha = expg(m_i[r] - mnew);
      m_i[r] = mnew;
      const float p0 = expg(v0 - mnew);
      const float p1 = expg(v1 - mnew);
      float rs = p0 + p1;
      rs += __shfl_xor(rs, 1);
      rs += __shfl_xor(rs, 2);
      rs += __shfl_xor(rs, 4);
      rs += __shfl_xor(rs, 8);
      l_i[r] = l_i[r] * alpha + rs;
#pragma unroll
      for (int dt = 0; dt < 32; ++dt) o[dt][r] *= alpha;
      Pb2[(wave * 16 + qr) * PB_S + l15]      = f2bf(p0);
      Pb2[(wave * 16 + qr) * PB_S + 16 + l15] = f2bf(p1);
    }
    __syncthreads();

    const short8 ap = *(const short8*)(&Pb2[(wave * 16 + l15) * PB_S + quad * 8]);
#pragma unroll
    for (int dt = 0; dt < 32; ++dt) {
      short8 bv = *(const short8*)(&KsmT[(dt * 16 + l15) * KST_S + quad * 8]);
      o[dt] = __builtin_amdgcn_mfma_f32_16x16x32_bf16(ap, bv, o[dt], 0, 0, 0);
    }
  }

#pragma unroll
  for (int r = 0; r < 4; ++r) {
    const float inv = 1.0f / fmaxf(l_i[r], 1e-30f);
    float* po = out + ((size_t)b * NN + (qw + quad * 4 + r)) * DD + l15;
#pragma unroll
    for (int dt = 0; dt < 32; ++dt)
      po[dt * 16] = o[dt][r] * inv;
  }
}

extern "C" void kernel_launch(void* const* d_in, const int* in_sizes, int n_in,
                              void* d_out, int out_size, void* d_ws, size_t ws_size,
                              hipStream_t stream) {
  const float* X   = (const float*)d_in[0];   // node_features fp32
  // d_in[1] = nodes (unused by forward)
  const int*   adj = (const int*)d_in[2];     // adj_list int32
  float*       out = (float*)d_out;           // fp32 output
  if (d_ws && ws_size >= WS_NEED) {
    short* W = (short*)d_ws;
    hipLaunchKernelGGL(xcvt, dim3(4096), dim3(256), 0, stream, X, W);
    hipLaunchKernelGGL(attn_fwd_v2, dim3(NB * (NN / QT)), dim3(256), 0, stream,
                       X, W, adj, out);
  } else {
    hipLaunchKernelGGL(attn_fwd, dim3(NB * (NN / QT)), dim3(256), 0, stream,
                       X, adj, out);
  }
}